// Round 2
// baseline (6807.229 us; speedup 1.0000x reference)
//
#include <hip/hip_runtime.h>

#define NB 4
#define NN 50000

// ---- workspace byte offsets (total ~196.3 MiB) ----
#define H0B  0L
#define H1B  51200000L
#define VTB  102400000L
#define QB   153600000L
#define KKB  179200000L
#define RMB  204800000L
#define V20B 205600000L
#define V21B 205731072L
#define KSB  205862144L
#define GMB  205863168L
#define NZERO 65796   // uints to zero starting at V20B

__device__ __forceinline__ unsigned short f2bf(float f){
  unsigned u = __float_as_uint(f);
  return (unsigned short)((u + 0x7FFFu + ((u>>16)&1u)) >> 16);
}
__device__ __forceinline__ float bf2f(unsigned short s){
  return __uint_as_float(((unsigned)s)<<16);
}
__device__ __forceinline__ unsigned pk2(float a, float b){
  return (unsigned)f2bf(a) | ((unsigned)f2bf(b)<<16);
}
__device__ __forceinline__ uint4 pk8(const float* f){
  uint4 o; o.x=pk2(f[0],f[1]); o.y=pk2(f[2],f[3]);
  o.z=pk2(f[4],f[5]); o.w=pk2(f[6],f[7]); return o;
}
__device__ __forceinline__ void up8(uint4 v, float* f){
  f[0]=bf2f((unsigned short)(v.x&0xFFFFu)); f[1]=bf2f((unsigned short)(v.x>>16));
  f[2]=bf2f((unsigned short)(v.y&0xFFFFu)); f[3]=bf2f((unsigned short)(v.y>>16));
  f[4]=bf2f((unsigned short)(v.z&0xFFFFu)); f[5]=bf2f((unsigned short)(v.z>>16));
  f[6]=bf2f((unsigned short)(v.w&0xFFFFu)); f[7]=bf2f((unsigned short)(v.w>>16));
}
__device__ __forceinline__ unsigned encOrd(float f){
  unsigned u = __float_as_uint(f);
  return (u & 0x80000000u) ? ~u : (u | 0x80000000u);
}
__device__ __forceinline__ float decOrd(unsigned u){
  return (u & 0x80000000u) ? __uint_as_float(u & 0x7fffffffu)
                           : __uint_as_float(~u);
}

__global__ void k_init(unsigned* __restrict__ z){
  int i = blockIdx.x*256 + threadIdx.x;
  if (i < NZERO) z[i] = 0u;
}

// ---------- pass1: h0(bf16), q(bf16), k'(bf16), rm(f32), global key max ----
__global__ __launch_bounds__(256) void k_pass1(
  const float* __restrict__ x, const float* __restrict__ node_emb,
  const float* __restrict__ time_emb, const float* __restrict__ week_emb,
  const float* __restrict__ W_in, const float* __restrict__ b_in,
  const float* __restrict__ W1, const float* __restrict__ b1,
  const float* __restrict__ W2, const float* __restrict__ b2,
  const float* __restrict__ proj, char* __restrict__ wsb)
{
  const int b = blockIdx.y;
  const int n = blockIdx.x*256 + threadIdx.x;
  const bool act = (n < NN);
  float kmx = -3.0e38f;
  if (act) {
    const long row = (long)b*NN + n;
    float xr[36];
    {
      const float4* xp = (const float4*)(x + row*36);
      #pragma unroll
      for (int i=0;i<9;i++){ float4 t=xp[i]; xr[4*i]=t.x; xr[4*i+1]=t.y; xr[4*i+2]=t.z; xr[4*i+3]=t.w; }
    }
    int tidx = (int)(xr[34]*288.0f); tidx = tidx<0?0:(tidx>287?287:tidx);
    int widx = (int)(xr[35]);        widx = widx<0?0:(widx>6?6:widx);
    uint4* h0q = (uint4*)(wsb + H0B) + row*16;
    // inp = x36 @ W_in^T + b_in -> h0[0:32]
    float hh[32];
    #pragma unroll 1
    for (int jj=0;jj<8;jj++){
      #pragma unroll
      for (int jl=0;jl<4;jl++){
        const int j = jj*4+jl;
        const float* w = W_in + j*36;
        float a0=0.f,a1=0.f,a2=0.f,a3=0.f;
        #pragma unroll
        for (int i=0;i<36;i+=4){ a0+=xr[i]*w[i]; a1+=xr[i+1]*w[i+1]; a2+=xr[i+2]*w[i+2]; a3+=xr[i+3]*w[i+3]; }
        hh[j] = b_in[j] + ((a0+a1)+(a2+a3));
      }
    }
    #pragma unroll
    for (int c=0;c<4;c++) h0q[c] = pk8(hh + 8*c);
    // xg = [ne, te, we]
    float xg[96];
    {
      const float4* p0 = (const float4*)(node_emb + (long)n*32);
      const float4* p1 = (const float4*)(time_emb + (long)tidx*32);
      const float4* p2 = (const float4*)(week_emb + (long)widx*32);
      #pragma unroll
      for (int i=0;i<8;i++){ float4 t=p0[i]; xg[4*i]=t.x; xg[4*i+1]=t.y; xg[4*i+2]=t.z; xg[4*i+3]=t.w; }
      #pragma unroll
      for (int i=0;i<8;i++){ float4 t=p1[i]; xg[32+4*i]=t.x; xg[32+4*i+1]=t.y; xg[32+4*i+2]=t.z; xg[32+4*i+3]=t.w; }
      #pragma unroll
      for (int i=0;i<8;i++){ float4 t=p2[i]; xg[64+4*i]=t.x; xg[64+4*i+1]=t.y; xg[64+4*i+2]=t.z; xg[64+4*i+3]=t.w; }
    }
    #pragma unroll
    for (int c=0;c<12;c++) h0q[4+c] = pk8(xg + 8*c);

    const float DSC = 0.42044820762685725f;   // 32^-0.25
    float dash[64];
    // ---- query side (W1) ----
    #pragma unroll
    for (int m=0;m<64;m++) dash[m]=0.f;
    float diag = 0.f;
    #pragma unroll 1
    for (int j=0;j<32;j++){
      const float* w = W1 + j*96;
      float a0=0.f,a1=0.f,a2=0.f,a3=0.f;
      #pragma unroll
      for (int i=0;i<96;i+=4){ a0+=xg[i]*w[i]; a1+=xg[i+1]*w[i+1]; a2+=xg[i+2]*w[i+2]; a3+=xg[i+3]*w[i+3]; }
      float dj = (b1[j] + ((a0+a1)+(a2+a3))) * DSC;
      diag += dj*dj;
      const float* pr = proj + j;
      #pragma unroll
      for (int m=0;m<64;m++) dash[m] += dj * pr[m*32];
    }
    diag *= 0.5f;
    float mx = dash[0];
    #pragma unroll
    for (int m=1;m<64;m++) mx = fmaxf(mx, dash[m]);
    uint4* qq = (uint4*)(wsb + QB) + row*8;
    #pragma unroll
    for (int mm=0;mm<8;mm++){
      float t[8];
      #pragma unroll
      for (int e=0;e<8;e++) t[e] = 0.125f*(__expf(dash[8*mm+e]-diag-mx)+1e-6f);
      qq[mm] = pk8(t);
    }
    // ---- key side (W2) ----
    #pragma unroll
    for (int m=0;m<64;m++) dash[m]=0.f;
    diag = 0.f;
    #pragma unroll 1
    for (int j=0;j<32;j++){
      const float* w = W2 + j*96;
      float a0=0.f,a1=0.f,a2=0.f,a3=0.f;
      #pragma unroll
      for (int i=0;i<96;i+=4){ a0+=xg[i]*w[i]; a1+=xg[i+1]*w[i+1]; a2+=xg[i+2]*w[i+2]; a3+=xg[i+3]*w[i+3]; }
      float dj = (b2[j] + ((a0+a1)+(a2+a3))) * DSC;
      diag += dj*dj;
      const float* pr = proj + j;
      #pragma unroll
      for (int m=0;m<64;m++) dash[m] += dj * pr[m*32];
    }
    diag *= 0.5f;
    kmx = dash[0];
    #pragma unroll
    for (int m=1;m<64;m++) kmx = fmaxf(kmx, dash[m]);
    uint4* kq = (uint4*)(wsb + KKB) + row*8;
    #pragma unroll
    for (int mm=0;mm<8;mm++){
      float t[8];
      #pragma unroll
      for (int e=0;e<8;e++) t[e] = __expf(dash[8*mm+e]-kmx);   // k' in (0,1]
      kq[mm] = pk8(t);
    }
    ((float*)(wsb + RMB))[row] = kmx - diag;   // rm' = max(dash) - diag
  }
  // block-reduce max(dash) -> atomicMax per batch
  #pragma unroll
  for (int off=32; off>0; off>>=1) kmx = fmaxf(kmx, __shfl_xor(kmx, off));
  __shared__ float wred[4];
  if ((threadIdx.x & 63)==0) wred[threadIdx.x>>6] = kmx;
  __syncthreads();
  if (threadIdx.x==0){
    float m2 = fmaxf(fmaxf(wred[0],wred[1]), fmaxf(wred[2],wred[3]));
    atomicMax((unsigned*)(wsb + GMB) + b, encOrd(m2));
  }
}

// ---------- GLU: v = sigmoid(h@wi^T+bi)*(h@wo^T+bo), bf16 out --------------
__device__ __forceinline__ void glu128_bf(const float* h,
    const float* __restrict__ wi, const float* __restrict__ bi,
    const float* __restrict__ wo, const float* __restrict__ bo,
    uint2* __restrict__ vr)
{
  #pragma unroll 1
  for (int jj=0;jj<32;jj++){
    float o[4];
    #pragma unroll
    for (int jl=0;jl<4;jl++){
      const int j = jj*4+jl;
      const float* wiR = wi + j*128;
      const float* woR = wo + j*128;
      float a0=0.f,a1=0.f,a2=0.f,a3=0.f,c0=0.f,c1=0.f,c2=0.f,c3=0.f;
      #pragma unroll
      for (int i=0;i<128;i+=4){
        a0+=h[i]*wiR[i]; a1+=h[i+1]*wiR[i+1]; a2+=h[i+2]*wiR[i+2]; a3+=h[i+3]*wiR[i+3];
        c0+=h[i]*woR[i]; c1+=h[i+1]*woR[i+1]; c2+=h[i+2]*woR[i+2]; c3+=h[i+3]*woR[i+3];
      }
      float a = bi[j]+((a0+a1)+(a2+a3));
      float c = bo[j]+((c0+c1)+(c2+c3));
      o[jl] = c / (1.0f + __expf(-a));
    }
    uint2 p; p.x = pk2(o[0],o[1]); p.y = pk2(o[2],o[3]);
    vr[jj] = p;
  }
}

// ---------- pass2: finalize k; v0 = GLU0(h0) -------------------------------
__global__ __launch_bounds__(256) void k_pass2(
  const float* __restrict__ wi, const float* __restrict__ bi,
  const float* __restrict__ wo, const float* __restrict__ bo,
  char* __restrict__ wsb)
{
  const int b = blockIdx.y;
  const int n = blockIdx.x*256 + threadIdx.x;
  if (n >= NN) return;
  const long row = (long)b*NN + n;
  const float gm = decOrd(((const unsigned*)(wsb + GMB))[b]);
  const float scale = __expf(((const float*)(wsb + RMB))[row] - gm);
  uint4* kq = (uint4*)(wsb + KKB) + row*8;
  #pragma unroll
  for (int mm=0;mm<8;mm++){
    float t[8]; up8(kq[mm], t);
    #pragma unroll
    for (int e=0;e<8;e++) t[e] = 0.125f*(t[e]*scale + 1e-6f);
    kq[mm] = pk8(t);
  }
  float h[128];
  const uint4* h0q = (const uint4*)(wsb + H0B) + row*16;
  #pragma unroll
  for (int c=0;c<16;c++) up8(h0q[c], h + 8*c);
  glu128_bf(h, wi, bi, wo, bo, (uint2*)(wsb + VTB) + row*32);
}

// ---------- ksum ------------------------------------------------------------
__global__ __launch_bounds__(256) void k_ksum(char* __restrict__ wsb){
  const int b = blockIdx.y;
  const int r0 = blockIdx.x*512;
  const int m2 = threadIdx.x & 31;   // uint index: covers m=2*m2, 2*m2+1
  const int rq = threadIdx.x >> 5;
  const int rend = min(r0+512, NN);
  const unsigned* kk = (const unsigned*)(wsb + KKB) + (long)b*NN*32;
  float a0=0.f, a1=0.f;
  for (int r=r0+rq; r<rend; r+=8){
    unsigned u = kk[(long)r*32 + m2];
    a0 += bf2f((unsigned short)(u&0xFFFFu));
    a1 += bf2f((unsigned short)(u>>16));
  }
  __shared__ float red0[8][32], red1[8][32];
  red0[rq][m2]=a0; red1[rq][m2]=a1;
  __syncthreads();
  if (threadIdx.x < 32){
    float s0=0.f, s1=0.f;
    #pragma unroll
    for (int q=0;q<8;q++){ s0+=red0[q][threadIdx.x]; s1+=red1[q][threadIdx.x]; }
    float* ks = (float*)(wsb + KSB) + b*64;
    atomicAdd(ks + 2*threadIdx.x,     s0);
    atomicAdd(ks + 2*threadIdx.x + 1, s1);
  }
}

// ---------- v2x[b][m][d] = sum_n k[n][m]*v[n][d] ---------------------------
__global__ __launch_bounds__(256) void k_reduce(const char* __restrict__ wsb,
                                                const unsigned short* __restrict__ vt,
                                                float* __restrict__ v2x)
{
  const int b  = blockIdx.y;
  const int r0 = blockIdx.x*512;
  __shared__ unsigned short klds[64*64];
  __shared__ unsigned short vlds[64*128];
  const int tid = threadIdx.x;
  const int mg = tid >> 4;   // m = mg*4 .. +3
  const int dg = tid & 15;   // d = dg*8 .. +7
  float acc[4][8];
  #pragma unroll
  for (int f=0;f<4;f++)
    #pragma unroll
    for (int e=0;e<8;e++) acc[f][e]=0.f;
  const uint4* kbase = (const uint4*)(wsb + KKB) + (long)b*NN*8;
  const uint4* vbase = (const uint4*)vt + (long)b*NN*16;
  const int rend = min(r0+512, NN);
  for (int t0=r0; t0<rend; t0+=64){
    __syncthreads();
    #pragma unroll
    for (int e=0;e<2;e++){
      int f = tid + 256*e;                 // 512 uint4 for k tile
      int rr = f >> 3, c = f & 7;
      int gr = t0 + rr;
      uint4 val = {0u,0u,0u,0u};
      if (gr < NN) val = kbase[(long)gr*8 + c];
      ((uint4*)klds)[f] = val;
    }
    #pragma unroll
    for (int e=0;e<4;e++){
      int f = tid + 256*e;                 // 1024 uint4 for v tile
      int rr = f >> 4, c = f & 15;
      int gr = t0 + rr;
      uint4 val = {0u,0u,0u,0u};
      if (gr < NN) val = vbase[(long)gr*16 + c];
      ((uint4*)vlds)[f] = val;
    }
    __syncthreads();
    #pragma unroll 2
    for (int r=0;r<64;r++){
      uint2 kv = ((const uint2*)klds)[r*16 + mg];
      uint4 vv = ((const uint4*)vlds)[r*16 + dg];
      float kkv[4] = { bf2f((unsigned short)(kv.x&0xFFFFu)), bf2f((unsigned short)(kv.x>>16)),
                       bf2f((unsigned short)(kv.y&0xFFFFu)), bf2f((unsigned short)(kv.y>>16)) };
      float vvv[8]; up8(vv, vvv);
      #pragma unroll
      for (int f=0;f<4;f++)
        #pragma unroll
        for (int e=0;e<8;e++) acc[f][e] += kkv[f]*vvv[e];
    }
  }
  #pragma unroll
  for (int f=0;f<4;f++)
    #pragma unroll
    for (int e=0;e<8;e++)
      atomicAdd(&v2x[(long)b*8192 + (mg*4+f)*128 + dg*8+e], acc[f][e]);
}

// ---------- pass3: attn0 + LN0 -> h1; v1 = GLU1(h1) ------------------------
__global__ __launch_bounds__(256) void k_pass3(
  const float* __restrict__ wi1, const float* __restrict__ bi1,
  const float* __restrict__ wo1, const float* __restrict__ bo1,
  const float* __restrict__ g0, const float* __restrict__ bt0,
  char* __restrict__ wsb)
{
  const int b = blockIdx.y;
  const int n = blockIdx.x*256 + threadIdx.x;
  __shared__ float v2s[8192];
  __shared__ float kss[64];
  {
    const float* v2g = (const float*)(wsb + V20B) + (long)b*8192;
    for (int i=threadIdx.x; i<8192; i+=256) v2s[i] = v2g[i];
    if (threadIdx.x < 64) kss[threadIdx.x] = ((const float*)(wsb + KSB))[b*64 + threadIdx.x];
  }
  __syncthreads();
  if (n >= NN) return;
  const long row = (long)b*NN + n;
  float r[128];
  #pragma unroll
  for (int d=0;d<128;d++) r[d]=0.f;
  float out2 = 0.f;
  const uint4* qq = (const uint4*)(wsb + QB) + row*8;
  #pragma unroll 1
  for (int mc=0;mc<8;mc++){
    float qa[8]; up8(qq[mc], qa);
    #pragma unroll 1
    for (int e=0;e<8;e++){
      const int m = mc*8+e;
      out2 += qa[e]*kss[m];
      const float4* vrow = (const float4*)(v2s + m*128);
      #pragma unroll
      for (int d4=0;d4<32;d4++){
        float4 v = vrow[d4];
        r[4*d4]   += qa[e]*v.x;
        r[4*d4+1] += qa[e]*v.y;
        r[4*d4+2] += qa[e]*v.z;
        r[4*d4+3] += qa[e]*v.w;
      }
    }
  }
  const float inv = 1.0f/out2;
  const uint4* h0q = (const uint4*)(wsb + H0B) + row*16;
  #pragma unroll
  for (int c=0;c<16;c++){
    float t[8]; up8(h0q[c], t);
    #pragma unroll
    for (int e=0;e<8;e++) r[8*c+e] = r[8*c+e]*inv + t[e];
  }
  float mu=0.f;
  #pragma unroll
  for (int d=0;d<128;d++) mu += r[d];
  mu *= (1.0f/128.0f);
  float var=0.f;
  #pragma unroll
  for (int d=0;d<128;d++){ float e=r[d]-mu; var += e*e; }
  var *= (1.0f/128.0f);
  const float rs = rsqrtf(var + 1e-5f);
  uint4* h1q = (uint4*)(wsb + H1B) + row*16;
  #pragma unroll
  for (int c=0;c<16;c++){
    float t[8];
    #pragma unroll
    for (int e=0;e<8;e++){ t[e] = (r[8*c+e]-mu)*rs*g0[8*c+e]+bt0[8*c+e]; r[8*c+e]=t[e]; }
    h1q[c] = pk8(t);
  }
  glu128_bf(r, wi1, bi1, wo1, bo1, (uint2*)(wsb + VTB) + row*32);
}

// ---------- pass4: attn1 + LN1 + regression head ---------------------------
__global__ __launch_bounds__(256) void k_pass4(
  const float* __restrict__ W_reg, const float* __restrict__ b_reg,
  const float* __restrict__ g1, const float* __restrict__ bt1,
  char* __restrict__ wsb, float* __restrict__ out)
{
  const int b = blockIdx.y;
  const int n = blockIdx.x*256 + threadIdx.x;
  __shared__ float v2s[8192];
  __shared__ float kss[64];
  {
    const float* v2g = (const float*)(wsb + V21B) + (long)b*8192;
    for (int i=threadIdx.x; i<8192; i+=256) v2s[i] = v2g[i];
    if (threadIdx.x < 64) kss[threadIdx.x] = ((const float*)(wsb + KSB))[b*64 + threadIdx.x];
  }
  __syncthreads();
  if (n >= NN) return;
  const long row = (long)b*NN + n;
  float r[128];
  #pragma unroll
  for (int d=0;d<128;d++) r[d]=0.f;
  float out2 = 0.f;
  const uint4* qq = (const uint4*)(wsb + QB) + row*8;
  #pragma unroll 1
  for (int mc=0;mc<8;mc++){
    float qa[8]; up8(qq[mc], qa);
    #pragma unroll 1
    for (int e=0;e<8;e++){
      const int m = mc*8+e;
      out2 += qa[e]*kss[m];
      const float4* vrow = (const float4*)(v2s + m*128);
      #pragma unroll
      for (int d4=0;d4<32;d4++){
        float4 v = vrow[d4];
        r[4*d4]   += qa[e]*v.x;
        r[4*d4+1] += qa[e]*v.y;
        r[4*d4+2] += qa[e]*v.z;
        r[4*d4+3] += qa[e]*v.w;
      }
    }
  }
  const float inv = 1.0f/out2;
  const uint4* h1q = (const uint4*)(wsb + H1B) + row*16;
  #pragma unroll
  for (int c=0;c<16;c++){
    float t[8]; up8(h1q[c], t);
    #pragma unroll
    for (int e=0;e<8;e++) r[8*c+e] = r[8*c+e]*inv + t[e];
  }
  float mu=0.f;
  #pragma unroll
  for (int d=0;d<128;d++) mu += r[d];
  mu *= (1.0f/128.0f);
  float var=0.f;
  #pragma unroll
  for (int d=0;d<128;d++){ float e=r[d]-mu; var += e*e; }
  var *= (1.0f/128.0f);
  const float rs = rsqrtf(var + 1e-5f);
  #pragma unroll
  for (int d=0;d<128;d++) r[d] = (r[d]-mu)*rs*g1[d]+bt1[d];
  // y = relu([h0, h2]) @ W_reg^T + b_reg
  float y[12];
  #pragma unroll
  for (int t=0;t<12;t++) y[t] = b_reg[t];
  const uint4* h0q = (const uint4*)(wsb + H0B) + row*16;
  #pragma unroll 1
  for (int c=0;c<16;c++){
    float u[8]; up8(h0q[c], u);
    #pragma unroll
    for (int e=0;e<8;e++){
      float uv = fmaxf(u[e], 0.f);
      const int col = 8*c+e;
      #pragma unroll
      for (int t=0;t<12;t++) y[t] += uv*W_reg[t*256+col];
    }
  }
  #pragma unroll 1
  for (int d=0;d<128;d++){
    float uv = fmaxf(r[d],0.f);
    #pragma unroll
    for (int t=0;t<12;t++) y[t] += uv*W_reg[t*256+128+d];
  }
  #pragma unroll
  for (int t=0;t<12;t++) out[((long)b*12+t)*NN + n] = y[t];
}

extern "C" void kernel_launch(void* const* d_in, const int* in_sizes, int n_in,
                              void* d_out, int out_size, void* d_ws, size_t ws_size,
                              hipStream_t stream)
{
  const float* x        = (const float*)d_in[0];
  const float* node_emb = (const float*)d_in[1];
  const float* time_emb = (const float*)d_in[2];
  const float* week_emb = (const float*)d_in[3];
  const float* W_in     = (const float*)d_in[4];
  const float* b_in     = (const float*)d_in[5];
  const float* W1       = (const float*)d_in[6];
  const float* b1       = (const float*)d_in[7];
  const float* W2       = (const float*)d_in[8];
  const float* b2       = (const float*)d_in[9];
  const float* W_reg    = (const float*)d_in[10];
  const float* b_reg    = (const float*)d_in[11];
  const float* proj     = (const float*)d_in[12];
  const float* fc_in0_w = (const float*)d_in[13];
  const float* fc_in0_b = (const float*)d_in[14];
  const float* fc_out0_w= (const float*)d_in[15];
  const float* fc_out0_b= (const float*)d_in[16];
  const float* ln0_g    = (const float*)d_in[17];
  const float* ln0_b    = (const float*)d_in[18];
  const float* fc_in1_w = (const float*)d_in[19];
  const float* fc_in1_b = (const float*)d_in[20];
  const float* fc_out1_w= (const float*)d_in[21];
  const float* fc_out1_b= (const float*)d_in[22];
  const float* ln1_g    = (const float*)d_in[23];
  const float* ln1_b    = (const float*)d_in[24];
  char* wsb  = (char*)d_ws;
  float* out = (float*)d_out;

  dim3 rowgrid((NN+255)/256, NB);
  dim3 redgrid((NN+511)/512, NB);

  k_init<<<dim3((NZERO+255)/256), dim3(256), 0, stream>>>((unsigned*)(wsb + V20B));
  k_pass1<<<rowgrid, 256, 0, stream>>>(x, node_emb, time_emb, week_emb,
                                       W_in, b_in, W1, b1, W2, b2, proj, wsb);
  k_pass2<<<rowgrid, 256, 0, stream>>>(fc_in0_w, fc_in0_b, fc_out0_w, fc_out0_b, wsb);
  k_ksum <<<redgrid, 256, 0, stream>>>(wsb);
  k_reduce<<<redgrid, 256, 0, stream>>>(wsb, (const unsigned short*)(wsb + VTB),
                                        (float*)(wsb + V20B));
  k_pass3<<<rowgrid, 256, 0, stream>>>(fc_in1_w, fc_in1_b, fc_out1_w, fc_out1_b,
                                       ln0_g, ln0_b, wsb);
  k_reduce<<<redgrid, 256, 0, stream>>>(wsb, (const unsigned short*)(wsb + VTB),
                                        (float*)(wsb + V21B));
  k_pass4<<<rowgrid, 256, 0, stream>>>(W_reg, b_reg, ln1_g, ln1_b, wsb, out);
}

// Round 3
// 1017.907 us; speedup vs baseline: 6.6875x; 6.6875x over previous
//
#include <hip/hip_runtime.h>

#define NB 4
#define NN 50000

// ---- workspace byte offsets (total ~205.1 MB, < proven 205.9 MB) ----
#define H0B   0L
#define H1B   51200000L
#define VTB   102400000L     // v (GLU output, bf16); start doubles as RM (fp32) before GLU0
#define RMB   102400000L
#define QB    153600000L
#define KKB   179200000L
#define WBFB  204800000L     // bf16 weights: layer0 [256][128], layer1 at +65536B
#define V2FB  204931072L     // fp32 v2x [4][64][128]
#define V2TB  205062144L     // bf16 v2x^T+ksum [4][144][64]
#define KSB   205135872L     // fp32 ksum [4][64]
#define GMB   205135872L + 1024L

typedef short short8_t __attribute__((ext_vector_type(8)));
typedef float f32x4 __attribute__((ext_vector_type(4)));

__device__ __forceinline__ unsigned short f2bf(float f){
  unsigned u = __float_as_uint(f);
  return (unsigned short)((u + 0x7FFFu + ((u>>16)&1u)) >> 16);
}
__device__ __forceinline__ float bf2f(unsigned short s){
  return __uint_as_float(((unsigned)s)<<16);
}
__device__ __forceinline__ unsigned pk2(float a, float b){
  return (unsigned)f2bf(a) | ((unsigned)f2bf(b)<<16);
}
__device__ __forceinline__ uint4 pk8(const float* f){
  uint4 o; o.x=pk2(f[0],f[1]); o.y=pk2(f[2],f[3]);
  o.z=pk2(f[4],f[5]); o.w=pk2(f[6],f[7]); return o;
}
__device__ __forceinline__ void up8(uint4 v, float* f){
  f[0]=bf2f((unsigned short)(v.x&0xFFFFu)); f[1]=bf2f((unsigned short)(v.x>>16));
  f[2]=bf2f((unsigned short)(v.y&0xFFFFu)); f[3]=bf2f((unsigned short)(v.y>>16));
  f[4]=bf2f((unsigned short)(v.z&0xFFFFu)); f[5]=bf2f((unsigned short)(v.z>>16));
  f[6]=bf2f((unsigned short)(v.w&0xFFFFu)); f[7]=bf2f((unsigned short)(v.w>>16));
}
__device__ __forceinline__ unsigned encOrd(float f){
  unsigned u = __float_as_uint(f);
  return (u & 0x80000000u) ? ~u : (u | 0x80000000u);
}
__device__ __forceinline__ float decOrd(unsigned u){
  return (u & 0x80000000u) ? __uint_as_float(u & 0x7fffffffu)
                           : __uint_as_float(~u);
}

// ---- zero ksum + gmax ----
__global__ void k_init0(char* __restrict__ wsb){
  int t = threadIdx.x;
  ((float*)(wsb + KSB))[t] = 0.0f;
  if (t < 4) ((unsigned*)(wsb + GMB))[t] = 0u;   // any real encodes > 0
}
// ---- zero v2x fp32 ----
__global__ void k_initv2(char* __restrict__ wsb){
  int i = blockIdx.x*256 + threadIdx.x;
  if (i < 32768) ((float*)(wsb + V2FB))[i] = 0.0f;
}
// ---- convert GLU weights to bf16 [n=0..255][k=0..127], n<128: wi, n>=128: wo
__global__ void k_wcvt(const float* __restrict__ wi0, const float* __restrict__ wo0,
                       const float* __restrict__ wi1, const float* __restrict__ wo1,
                       char* __restrict__ wsb){
  int idx = blockIdx.x*256 + threadIdx.x;       // 65536 total
  if (idx >= 65536) return;
  int l = idx >> 15, r = (idx >> 7) & 255, c = idx & 127;
  const float* src = (l==0) ? ((r<128)? wi0 : wo0) : ((r<128)? wi1 : wo1);
  float v = src[(r&127)*128 + c];
  ((unsigned short*)(wsb + WBFB))[l*32768 + r*128 + c] = f2bf(v);
}

// ---------- pass1: h0(bf16), q(bf16), k'(bf16), rm(f32), global key max ----
__global__ __launch_bounds__(256) void k_pass1(
  const float* __restrict__ x, const float* __restrict__ node_emb,
  const float* __restrict__ time_emb, const float* __restrict__ week_emb,
  const float* __restrict__ W_in, const float* __restrict__ b_in,
  const float* __restrict__ W1, const float* __restrict__ b1,
  const float* __restrict__ W2, const float* __restrict__ b2,
  const float* __restrict__ proj, char* __restrict__ wsb)
{
  const int b = blockIdx.y;
  const int n = blockIdx.x*256 + threadIdx.x;
  const bool act = (n < NN);
  float kmx = -3.0e38f;
  if (act) {
    const long row = (long)b*NN + n;
    float xr[36];
    {
      const float4* xp = (const float4*)(x + row*36);
      #pragma unroll
      for (int i=0;i<9;i++){ float4 t=xp[i]; xr[4*i]=t.x; xr[4*i+1]=t.y; xr[4*i+2]=t.z; xr[4*i+3]=t.w; }
    }
    int tidx = (int)(xr[34]*288.0f); tidx = tidx<0?0:(tidx>287?287:tidx);
    int widx = (int)(xr[35]);        widx = widx<0?0:(widx>6?6:widx);
    uint4* h0q = (uint4*)(wsb + H0B) + row*16;
    float hh[32];
    #pragma unroll 1
    for (int jj=0;jj<8;jj++){
      #pragma unroll
      for (int jl=0;jl<4;jl++){
        const int j = jj*4+jl;
        const float* w = W_in + j*36;
        float a0=0.f,a1=0.f,a2=0.f,a3=0.f;
        #pragma unroll
        for (int i=0;i<36;i+=4){ a0+=xr[i]*w[i]; a1+=xr[i+1]*w[i+1]; a2+=xr[i+2]*w[i+2]; a3+=xr[i+3]*w[i+3]; }
        hh[j] = b_in[j] + ((a0+a1)+(a2+a3));
      }
    }
    #pragma unroll
    for (int c=0;c<4;c++) h0q[c] = pk8(hh + 8*c);
    float xg[96];
    {
      const float4* p0 = (const float4*)(node_emb + (long)n*32);
      const float4* p1 = (const float4*)(time_emb + (long)tidx*32);
      const float4* p2 = (const float4*)(week_emb + (long)widx*32);
      #pragma unroll
      for (int i=0;i<8;i++){ float4 t=p0[i]; xg[4*i]=t.x; xg[4*i+1]=t.y; xg[4*i+2]=t.z; xg[4*i+3]=t.w; }
      #pragma unroll
      for (int i=0;i<8;i++){ float4 t=p1[i]; xg[32+4*i]=t.x; xg[32+4*i+1]=t.y; xg[32+4*i+2]=t.z; xg[32+4*i+3]=t.w; }
      #pragma unroll
      for (int i=0;i<8;i++){ float4 t=p2[i]; xg[64+4*i]=t.x; xg[64+4*i+1]=t.y; xg[64+4*i+2]=t.z; xg[64+4*i+3]=t.w; }
    }
    #pragma unroll
    for (int c=0;c<12;c++) h0q[4+c] = pk8(xg + 8*c);

    const float DSC = 0.42044820762685725f;   // 32^-0.25
    float dash[64];
    #pragma unroll
    for (int m=0;m<64;m++) dash[m]=0.f;
    float diag = 0.f;
    #pragma unroll 1
    for (int j=0;j<32;j++){
      const float* w = W1 + j*96;
      float a0=0.f,a1=0.f,a2=0.f,a3=0.f;
      #pragma unroll
      for (int i=0;i<96;i+=4){ a0+=xg[i]*w[i]; a1+=xg[i+1]*w[i+1]; a2+=xg[i+2]*w[i+2]; a3+=xg[i+3]*w[i+3]; }
      float dj = (b1[j] + ((a0+a1)+(a2+a3))) * DSC;
      diag += dj*dj;
      const float* pr = proj + j;
      #pragma unroll
      for (int m=0;m<64;m++) dash[m] += dj * pr[m*32];
    }
    diag *= 0.5f;
    float mx = dash[0];
    #pragma unroll
    for (int m=1;m<64;m++) mx = fmaxf(mx, dash[m]);
    uint4* qq = (uint4*)(wsb + QB) + row*8;
    #pragma unroll
    for (int mm=0;mm<8;mm++){
      float t[8];
      #pragma unroll
      for (int e=0;e<8;e++) t[e] = 0.125f*(__expf(dash[8*mm+e]-diag-mx)+1e-6f);
      qq[mm] = pk8(t);
    }
    #pragma unroll
    for (int m=0;m<64;m++) dash[m]=0.f;
    diag = 0.f;
    #pragma unroll 1
    for (int j=0;j<32;j++){
      const float* w = W2 + j*96;
      float a0=0.f,a1=0.f,a2=0.f,a3=0.f;
      #pragma unroll
      for (int i=0;i<96;i+=4){ a0+=xg[i]*w[i]; a1+=xg[i+1]*w[i+1]; a2+=xg[i+2]*w[i+2]; a3+=xg[i+3]*w[i+3]; }
      float dj = (b2[j] + ((a0+a1)+(a2+a3))) * DSC;
      diag += dj*dj;
      const float* pr = proj + j;
      #pragma unroll
      for (int m=0;m<64;m++) dash[m] += dj * pr[m*32];
    }
    diag *= 0.5f;
    kmx = dash[0];
    #pragma unroll
    for (int m=1;m<64;m++) kmx = fmaxf(kmx, dash[m]);
    uint4* kq = (uint4*)(wsb + KKB) + row*8;
    #pragma unroll
    for (int mm=0;mm<8;mm++){
      float t[8];
      #pragma unroll
      for (int e=0;e<8;e++) t[e] = __expf(dash[8*mm+e]-kmx);   // k' in (0,1]
      kq[mm] = pk8(t);
    }
    ((float*)(wsb + RMB))[row] = kmx - diag;
  }
  #pragma unroll
  for (int off=32; off>0; off>>=1) kmx = fmaxf(kmx, __shfl_xor(kmx, off));
  __shared__ float wred[4];
  if ((threadIdx.x & 63)==0) wred[threadIdx.x>>6] = kmx;
  __syncthreads();
  if (threadIdx.x==0){
    float m2 = fmaxf(fmaxf(wred[0],wred[1]), fmaxf(wred[2],wred[3]));
    atomicMax((unsigned*)(wsb + GMB) + b, encOrd(m2));
  }
}

// ---------- finalize k = 0.125*(k'*exp(rm-gmax)+1e-6) ----------------------
__global__ __launch_bounds__(256) void k_kfin(char* __restrict__ wsb){
  const int b = blockIdx.y;
  const int n = blockIdx.x*256 + threadIdx.x;
  if (n >= NN) return;
  const long row = (long)b*NN + n;
  const float gm = decOrd(((const unsigned*)(wsb + GMB))[b]);
  const float scale = __expf(((const float*)(wsb + RMB))[row] - gm);
  uint4* kq = (uint4*)(wsb + KKB) + row*8;
  #pragma unroll
  for (int mm=0;mm<8;mm++){
    float t[8]; up8(kq[mm], t);
    #pragma unroll
    for (int e=0;e<8;e++) t[e] = 0.125f*(t[e]*scale + 1e-6f);
    kq[mm] = pk8(t);
  }
}

// ---------- MFMA GLU: v = sigmoid(h@wi^T+bi)*(h@wo^T+bo) -------------------
// h: [200000][128] bf16 row-major; wbf: [256][128] bf16 (n<128: wi, n>=128: wo)
__global__ __launch_bounds__(256) void k_glu(
  const unsigned short* __restrict__ h, const unsigned short* __restrict__ wbf,
  const float* __restrict__ bi, const float* __restrict__ bo,
  unsigned short* __restrict__ vout)
{
  const int lane = threadIdx.x & 63;
  const int wid  = threadIdx.x >> 6;
  const int c  = lane & 15;
  const int kg = lane >> 4;
  const long r0 = (long)blockIdx.x*64 + wid*16;     // 3125 blocks * 64 = 200000 exact
  const unsigned short* arow = h + (r0 + c)*128 + kg*8;
  f32x4 acc[16];
  #pragma unroll
  for (int f=0;f<16;f++) acc[f] = (f32x4){0.f,0.f,0.f,0.f};
  #pragma unroll
  for (int ks=0;ks<4;ks++){
    short8_t a = *(const short8_t*)(arow + ks*32);
    #pragma unroll
    for (int f=0;f<16;f++){
      short8_t bb = *(const short8_t*)(wbf + (f*16 + c)*128 + ks*32 + kg*8);
      acc[f] = __builtin_amdgcn_mfma_f32_16x16x32_bf16(a, bb, acc[f], 0, 0, 0);
    }
  }
  float bi_l[8], bo_l[8];
  #pragma unroll
  for (int f=0;f<8;f++){ bi_l[f] = bi[f*16+c]; bo_l[f] = bo[f*16+c]; }
  #pragma unroll
  for (int f=0;f<8;f++){
    #pragma unroll
    for (int j=0;j<4;j++){
      const long gr = r0 + kg*4 + j;
      float a  = acc[f][j]   + bi_l[f];
      float cc = acc[f+8][j] + bo_l[f];
      float o  = cc / (1.0f + __expf(-a));
      vout[gr*128 + f*16 + c] = f2bf(o);
    }
  }
}

// ---------- ksum ------------------------------------------------------------
__global__ __launch_bounds__(256) void k_ksum(char* __restrict__ wsb){
  const int b = blockIdx.y;
  const int r0 = blockIdx.x*512;
  const int m2 = threadIdx.x & 31;
  const int rq = threadIdx.x >> 5;
  const int rend = min(r0+512, NN);
  const unsigned* kk = (const unsigned*)(wsb + KKB) + (long)b*NN*32;
  float a0=0.f, a1=0.f;
  for (int r=r0+rq; r<rend; r+=8){
    unsigned u = kk[(long)r*32 + m2];
    a0 += bf2f((unsigned short)(u&0xFFFFu));
    a1 += bf2f((unsigned short)(u>>16));
  }
  __shared__ float red0[8][32], red1[8][32];
  red0[rq][m2]=a0; red1[rq][m2]=a1;
  __syncthreads();
  if (threadIdx.x < 32){
    float s0=0.f, s1=0.f;
    #pragma unroll
    for (int q=0;q<8;q++){ s0+=red0[q][threadIdx.x]; s1+=red1[q][threadIdx.x]; }
    float* ks = (float*)(wsb + KSB) + b*64;
    atomicAdd(ks + 2*threadIdx.x,     s0);
    atomicAdd(ks + 2*threadIdx.x + 1, s1);
  }
}

// ---------- v2x[b][m][d] = sum_n k[n][m]*v[n][d] ---------------------------
__global__ __launch_bounds__(256) void k_reduce(const char* __restrict__ wsb,
                                                const unsigned short* __restrict__ vt,
                                                float* __restrict__ v2x)
{
  const int b  = blockIdx.y;
  const int r0 = blockIdx.x*512;
  __shared__ unsigned short klds[64*64];
  __shared__ unsigned short vlds[64*128];
  const int tid = threadIdx.x;
  const int mg = tid >> 4;
  const int dg = tid & 15;
  float acc[4][8];
  #pragma unroll
  for (int f=0;f<4;f++)
    #pragma unroll
    for (int e=0;e<8;e++) acc[f][e]=0.f;
  const uint4* kbase = (const uint4*)(wsb + KKB) + (long)b*NN*8;
  const uint4* vbase = (const uint4*)vt + (long)b*NN*16;
  const int rend = min(r0+512, NN);
  for (int t0=r0; t0<rend; t0+=64){
    __syncthreads();
    #pragma unroll
    for (int e=0;e<2;e++){
      int f = tid + 256*e;
      int rr = f >> 3, cc = f & 7;
      int gr = t0 + rr;
      uint4 val = {0u,0u,0u,0u};
      if (gr < NN) val = kbase[(long)gr*8 + cc];
      ((uint4*)klds)[f] = val;
    }
    #pragma unroll
    for (int e=0;e<4;e++){
      int f = tid + 256*e;
      int rr = f >> 4, cc = f & 15;
      int gr = t0 + rr;
      uint4 val = {0u,0u,0u,0u};
      if (gr < NN) val = vbase[(long)gr*16 + cc];
      ((uint4*)vlds)[f] = val;
    }
    __syncthreads();
    #pragma unroll 2
    for (int r=0;r<64;r++){
      uint2 kv = ((const uint2*)klds)[r*16 + mg];
      uint4 vv = ((const uint4*)vlds)[r*16 + dg];
      float kkv[4] = { bf2f((unsigned short)(kv.x&0xFFFFu)), bf2f((unsigned short)(kv.x>>16)),
                       bf2f((unsigned short)(kv.y&0xFFFFu)), bf2f((unsigned short)(kv.y>>16)) };
      float vvv[8]; up8(vv, vvv);
      #pragma unroll
      for (int f=0;f<4;f++)
        #pragma unroll
        for (int e=0;e<8;e++) acc[f][e] += kkv[f]*vvv[e];
    }
  }
  #pragma unroll
  for (int f=0;f<4;f++)
    #pragma unroll
    for (int e=0;e<8;e++)
      atomicAdd(&v2x[(long)b*8192 + (mg*4+f)*128 + dg*8+e], acc[f][e]);
}

// ---------- v2t[b][n][m]: n<128: v2x[m][n]; n=128: ksum[m]; n>128: 0 -------
__global__ void k_v2cvt(char* __restrict__ wsb){
  int idx = blockIdx.x*256 + threadIdx.x;          // 4*144*64 = 36864
  if (idx >= 36864) return;
  int b = idx / 9216, rem = idx % 9216;
  int n = rem / 64, m = rem % 64;
  const float* v2f = (const float*)(wsb + V2FB);
  const float* ks  = (const float*)(wsb + KSB);
  float v = (n < 128) ? v2f[b*8192 + m*128 + n] : ((n==128) ? ks[b*64+m] : 0.f);
  ((unsigned short*)(wsb + V2TB))[b*9216 + n*64 + m] = f2bf(v);
}

// ---------- MFMA attn-apply + residual + LN -> h1 --------------------------
__global__ __launch_bounds__(256) void k_attnln(
  const char* __restrict__ wsb, const float* __restrict__ g0,
  const float* __restrict__ bt0)
{
  const int b = blockIdx.y;
  const int lane = threadIdx.x & 63;
  const int wid  = threadIdx.x >> 6;
  const int r0 = blockIdx.x*64 + wid*16;
  if (r0 >= NN) return;                          // NN%16==0: whole-wave validity
  const int c  = lane & 15;
  const int kg = lane >> 4;
  const unsigned short* q   = (const unsigned short*)(wsb + QB);
  const unsigned short* v2t = (const unsigned short*)(wsb + V2TB) + b*9216;
  const unsigned short* h0  = (const unsigned short*)(wsb + H0B);
  unsigned short* h1 = (unsigned short*)(wsb + H1B);
  const unsigned short* qrow = q + ((long)b*NN + r0 + c)*64 + kg*8;
  f32x4 acc[9];
  #pragma unroll
  for (int f=0;f<9;f++) acc[f] = (f32x4){0.f,0.f,0.f,0.f};
  #pragma unroll
  for (int ks=0;ks<2;ks++){
    short8_t a = *(const short8_t*)(qrow + ks*32);
    #pragma unroll
    for (int f=0;f<9;f++){
      short8_t bb = *(const short8_t*)(v2t + (f*16 + c)*64 + ks*32 + kg*8);
      acc[f] = __builtin_amdgcn_mfma_f32_16x16x32_bf16(a, bb, acc[f], 0, 0, 0);
    }
  }
  float inv[4];
  #pragma unroll
  for (int j=0;j<4;j++){
    float o2 = __shfl(acc[8][j], (lane & 48));   // col 128 = ksum dot
    inv[j] = 1.0f / o2;
  }
  float t[8][4];
  #pragma unroll
  for (int f=0;f<8;f++)
    #pragma unroll
    for (int j=0;j<4;j++){
      const long gr = (long)b*NN + r0 + kg*4 + j;
      t[f][j] = acc[f][j]*inv[j] + bf2f(h0[gr*128 + f*16 + c]);
    }
  float mu[4], rs[4];
  #pragma unroll
  for (int j=0;j<4;j++){
    float s = 0.f;
    #pragma unroll
    for (int f=0;f<8;f++) s += t[f][j];
    #pragma unroll
    for (int off=1; off<16; off<<=1) s += __shfl_xor(s, off);
    mu[j] = s * (1.0f/128.0f);
  }
  #pragma unroll
  for (int j=0;j<4;j++){
    float s = 0.f;
    #pragma unroll
    for (int f=0;f<8;f++){ float e = t[f][j]-mu[j]; s += e*e; }
    #pragma unroll
    for (int off=1; off<16; off<<=1) s += __shfl_xor(s, off);
    rs[j] = rsqrtf(s * (1.0f/128.0f) + 1e-5f);
  }
  float g_l[8], bt_l[8];
  #pragma unroll
  for (int f=0;f<8;f++){ g_l[f] = g0[f*16+c]; bt_l[f] = bt0[f*16+c]; }
  #pragma unroll
  for (int f=0;f<8;f++)
    #pragma unroll
    for (int j=0;j<4;j++){
      const long gr = (long)b*NN + r0 + kg*4 + j;
      float o = (t[f][j]-mu[j])*rs[j]*g_l[f] + bt_l[f];
      h1[gr*128 + f*16 + c] = f2bf(o);
    }
}

// ---------- MFMA attn-apply + residual(h1) + LN1 + regression head ---------
__global__ __launch_bounds__(256) void k_attnhead(
  const char* __restrict__ wsb, const float* __restrict__ g1,
  const float* __restrict__ bt1, const float* __restrict__ W_reg,
  const float* __restrict__ b_reg, float* __restrict__ out)
{
  const int b = blockIdx.y;
  const int lane = threadIdx.x & 63;
  const int wid  = threadIdx.x >> 6;
  const int r0 = blockIdx.x*64 + wid*16;
  if (r0 >= NN) return;
  const int c  = lane & 15;
  const int kg = lane >> 4;
  const unsigned short* q   = (const unsigned short*)(wsb + QB);
  const unsigned short* v2t = (const unsigned short*)(wsb + V2TB) + b*9216;
  const unsigned short* h0  = (const unsigned short*)(wsb + H0B);
  const unsigned short* h1  = (const unsigned short*)(wsb + H1B);
  const unsigned short* qrow = q + ((long)b*NN + r0 + c)*64 + kg*8;
  f32x4 acc[9];
  #pragma unroll
  for (int f=0;f<9;f++) acc[f] = (f32x4){0.f,0.f,0.f,0.f};
  #pragma unroll
  for (int ks=0;ks<2;ks++){
    short8_t a = *(const short8_t*)(qrow + ks*32);
    #pragma unroll
    for (int f=0;f<9;f++){
      short8_t bb = *(const short8_t*)(v2t + (f*16 + c)*64 + ks*32 + kg*8);
      acc[f] = __builtin_amdgcn_mfma_f32_16x16x32_bf16(a, bb, acc[f], 0, 0, 0);
    }
  }
  float inv[4];
  #pragma unroll
  for (int j=0;j<4;j++){
    float o2 = __shfl(acc[8][j], (lane & 48));
    inv[j] = 1.0f / o2;
  }
  float t[8][4], u0[8][4];
  #pragma unroll
  for (int f=0;f<8;f++)
    #pragma unroll
    for (int j=0;j<4;j++){
      const long gr = (long)b*NN + r0 + kg*4 + j;
      t[f][j]  = acc[f][j]*inv[j] + bf2f(h1[gr*128 + f*16 + c]);
      u0[f][j] = fmaxf(bf2f(h0[gr*128 + f*16 + c]), 0.f);
    }
  float mu[4], rs[4];
  #pragma unroll
  for (int j=0;j<4;j++){
    float s = 0.f;
    #pragma unroll
    for (int f=0;f<8;f++) s += t[f][j];
    #pragma unroll
    for (int off=1; off<16; off<<=1) s += __shfl_xor(s, off);
    mu[j] = s * (1.0f/128.0f);
  }
  #pragma unroll
  for (int j=0;j<4;j++){
    float s = 0.f;
    #pragma unroll
    for (int f=0;f<8;f++){ float e = t[f][j]-mu[j]; s += e*e; }
    #pragma unroll
    for (int off=1; off<16; off<<=1) s += __shfl_xor(s, off);
    rs[j] = rsqrtf(s * (1.0f/128.0f) + 1e-5f);
  }
  float g_l[8], bt_l[8];
  #pragma unroll
  for (int f=0;f<8;f++){ g_l[f] = g1[f*16+c]; bt_l[f] = bt1[f*16+c]; }
  #pragma unroll
  for (int f=0;f<8;f++)
    #pragma unroll
    for (int j=0;j<4;j++)
      t[f][j] = fmaxf((t[f][j]-mu[j])*rs[j]*g_l[f] + bt_l[f], 0.f);   // relu(h2)
  // head: y[t][row] = sum_c relu(h0)[c]*W[t][c] + relu(h2)[d]*W[t][128+d]
  float y[12][4];
  #pragma unroll
  for (int tt=0;tt<12;tt++)
    #pragma unroll
    for (int j=0;j<4;j++) y[tt][j] = 0.f;
  #pragma unroll
  for (int f=0;f<8;f++){
    #pragma unroll
    for (int tt=0;tt<12;tt++){
      float wl = W_reg[tt*256 + f*16 + c];
      float wh = W_reg[tt*256 + 128 + f*16 + c];
      #pragma unroll
      for (int j=0;j<4;j++) y[tt][j] += u0[f][j]*wl + t[f][j]*wh;
    }
  }
  #pragma unroll
  for (int tt=0;tt<12;tt++)
    #pragma unroll
    for (int j=0;j<4;j++){
      float s = y[tt][j];
      #pragma unroll
      for (int off=1; off<16; off<<=1) s += __shfl_xor(s, off);
      if (c == tt)
        out[((long)b*12 + tt)*NN + r0 + kg*4 + j] = s + b_reg[tt];
    }
}

extern "C" void kernel_launch(void* const* d_in, const int* in_sizes, int n_in,
                              void* d_out, int out_size, void* d_ws, size_t ws_size,
                              hipStream_t stream)
{
  const float* x        = (const float*)d_in[0];
  const float* node_emb = (const float*)d_in[1];
  const float* time_emb = (const float*)d_in[2];
  const float* week_emb = (const float*)d_in[3];
  const float* W_in     = (const float*)d_in[4];
  const float* b_in     = (const float*)d_in[5];
  const float* W1       = (const float*)d_in[6];
  const float* b1       = (const float*)d_in[7];
  const float* W2       = (const float*)d_in[8];
  const float* b2       = (const float*)d_in[9];
  const float* W_reg    = (const float*)d_in[10];
  const float* b_reg    = (const float*)d_in[11];
  const float* proj     = (const float*)d_in[12];
  const float* fc_in0_w = (const float*)d_in[13];
  const float* fc_in0_b = (const float*)d_in[14];
  const float* fc_out0_w= (const float*)d_in[15];
  const float* fc_out0_b= (const float*)d_in[16];
  const float* ln0_g    = (const float*)d_in[17];
  const float* ln0_b    = (const float*)d_in[18];
  const float* fc_in1_w = (const float*)d_in[19];
  const float* fc_in1_b = (const float*)d_in[20];
  const float* fc_out1_w= (const float*)d_in[21];
  const float* fc_out1_b= (const float*)d_in[22];
  const float* ln1_g    = (const float*)d_in[23];
  const float* ln1_b    = (const float*)d_in[24];
  char* wsb  = (char*)d_ws;
  float* out = (float*)d_out;

  dim3 rowgrid((NN+255)/256, NB);     // (196, 4)
  dim3 redgrid((NN+511)/512, NB);     // (98, 4)
  dim3 glugrid(3125);                 // 3125*64 = 200000 rows
  dim3 atngrid(782, NB);              // 782*64 >= 50000 per batch

  k_init0 <<<1, 256, 0, stream>>>(wsb);
  k_wcvt  <<<256, 256, 0, stream>>>(fc_in0_w, fc_out0_w, fc_in1_w, fc_out1_w, wsb);
  k_pass1 <<<rowgrid, 256, 0, stream>>>(x, node_emb, time_emb, week_emb,
                                        W_in, b_in, W1, b1, W2, b2, proj, wsb);
  k_kfin  <<<rowgrid, 256, 0, stream>>>(wsb);
  k_glu   <<<glugrid, 256, 0, stream>>>((const unsigned short*)(wsb + H0B),
                                        (const unsigned short*)(wsb + WBFB),
                                        fc_in0_b, fc_out0_b,
                                        (unsigned short*)(wsb + VTB));
  k_ksum  <<<redgrid, 256, 0, stream>>>(wsb);
  k_initv2<<<128, 256, 0, stream>>>(wsb);
  k_reduce<<<redgrid, 256, 0, stream>>>(wsb, (const unsigned short*)(wsb + VTB),
                                        (float*)(wsb + V2FB));
  k_v2cvt <<<144, 256, 0, stream>>>(wsb);
  k_attnln<<<atngrid, 256, 0, stream>>>(wsb, ln0_g, ln0_b);
  k_glu   <<<glugrid, 256, 0, stream>>>((const unsigned short*)(wsb + H1B),
                                        (const unsigned short*)(wsb + WBFB) + 32768,
                                        fc_in1_b, fc_out1_b,
                                        (unsigned short*)(wsb + VTB));
  k_initv2<<<128, 256, 0, stream>>>(wsb);
  k_reduce<<<redgrid, 256, 0, stream>>>(wsb, (const unsigned short*)(wsb + VTB),
                                        (float*)(wsb + V2FB));
  k_v2cvt <<<144, 256, 0, stream>>>(wsb);
  k_attnhead<<<atngrid, 256, 0, stream>>>(wsb, ln1_g, ln1_b, W_reg, b_reg, out);
}